// Round 1
// baseline (5786.966 us; speedup 1.0000x reference)
//
#include <hip/hip_runtime.h>

#define D 128
#define GROWS 32

// ---------------------------------------------------------------------------
// Aggregation: one edge handled by 32 threads (4 floats each, float4).
// atomicAdd f32 into agg[dst]; lane c==0 also counts degree (layer 1 only).
// ---------------------------------------------------------------------------
__global__ __launch_bounds__(256) void k_agg(const float* __restrict__ feat,
                                             const int* __restrict__ ei,
                                             float* __restrict__ agg,
                                             float* __restrict__ deg,
                                             int E, int do_deg)
{
    long idx = (long)blockIdx.x * blockDim.x + threadIdx.x;
    int e = (int)(idx >> 5);
    if (e >= E) return;
    int c = ((int)idx & 31) * 4;
    int src = ei[e];
    int dst = ei[E + e];
    const float4 v = *(const float4*)(feat + (size_t)src * D + c);
    float* a = agg + (size_t)dst * D + c;
    atomicAdd(a + 0, v.x);
    atomicAdd(a + 1, v.y);
    atomicAdd(a + 2, v.z);
    atomicAdd(a + 3, v.w);
    if (do_deg && c == 0) atomicAdd(deg + dst, 1.0f);
}

// ---------------------------------------------------------------------------
// Fused SAGE linear: out[r] = relu?( (agg[r]/max(deg,1)) @ Wl + b + xin[r] @ Wr )
// Block: 256 threads, 32 rows. LDS: row tile [32][256] (mean||x) + W chunk
// [64][128]. Thread (jg = t&31 -> 4 cols, rt = t>>5 -> 4 rows stride 8).
// ---------------------------------------------------------------------------
__global__ __launch_bounds__(256) void k_linear(const float* __restrict__ agg,
                                                const float* __restrict__ deg,
                                                const float* __restrict__ xin,
                                                const float* __restrict__ Wl,
                                                const float* __restrict__ bias,
                                                const float* __restrict__ Wr,
                                                float* __restrict__ out,
                                                int n, int relu)
{
    __shared__ float rows[GROWS][2 * D];   // 32 KB
    __shared__ float wbuf[64][D];          // 32 KB
    const int t  = threadIdx.x;
    const int r0 = blockIdx.x * GROWS;

    // stage [mean || x] rows (mean = agg/deg fused here)
    for (int f = t; f < GROWS * (2 * D / 4); f += 256) {
        int r  = f >> 6;
        int cc = (f & 63) * 4;
        int row = r0 + r;
        float4 v = make_float4(0.f, 0.f, 0.f, 0.f);
        if (row < n) {
            if (cc < D) {
                v = *(const float4*)(agg + (size_t)row * D + cc);
                float dinv = 1.0f / fmaxf(deg[row], 1.0f);
                v.x *= dinv; v.y *= dinv; v.z *= dinv; v.w *= dinv;
            } else {
                v = *(const float4*)(xin + (size_t)row * D + (cc - D));
            }
        }
        *(float4*)&rows[r][cc] = v;
    }

    const int j  = (t & 31) * 4;   // 4 output cols
    const int rt = t >> 5;         // 4 rows: rt, rt+8, rt+16, rt+24
    float acc[4][4];
    #pragma unroll
    for (int a = 0; a < 4; a++)
        #pragma unroll
        for (int b = 0; b < 4; b++) acc[a][b] = 0.f;

    for (int kb = 0; kb < 2 * D; kb += 64) {
        __syncthreads();           // wbuf reuse + (first iter) rows ready
        // stage 64 k-rows of stacked [Wl; Wr]
        for (int f = t; f < 64 * (D / 4); f += 256) {
            int kk = f >> 5;
            int cc = (f & 31) * 4;
            int kg = kb + kk;
            const float* ws = (kg < D) ? (Wl + (size_t)kg * D + cc)
                                       : (Wr + (size_t)(kg - D) * D + cc);
            *(float4*)&wbuf[kk][cc] = *(const float4*)ws;
        }
        __syncthreads();
        #pragma unroll 8
        for (int kk = 0; kk < 64; kk++) {
            float4 w = *(const float4*)&wbuf[kk][j];
            int k = kb + kk;
            #pragma unroll
            for (int ri = 0; ri < 4; ri++) {
                float rv = rows[rt + ri * 8][k];
                acc[ri][0] += rv * w.x;
                acc[ri][1] += rv * w.y;
                acc[ri][2] += rv * w.z;
                acc[ri][3] += rv * w.w;
            }
        }
    }

    float4 bv = *(const float4*)(bias + j);
    #pragma unroll
    for (int ri = 0; ri < 4; ri++) {
        int row = r0 + rt + ri * 8;
        if (row >= n) continue;
        float4 o;
        o.x = acc[ri][0] + bv.x;
        o.y = acc[ri][1] + bv.y;
        o.z = acc[ri][2] + bv.z;
        o.w = acc[ri][3] + bv.w;
        if (relu) {
            o.x = fmaxf(o.x, 0.f); o.y = fmaxf(o.y, 0.f);
            o.z = fmaxf(o.z, 0.f); o.w = fmaxf(o.w, 0.f);
        }
        *(float4*)(out + (size_t)row * D + j) = o;
    }
}

extern "C" void kernel_launch(void* const* d_in, const int* in_sizes, int n_in,
                              void* d_out, int out_size, void* d_ws, size_t ws_size,
                              hipStream_t stream)
{
    const float* x   = (const float*)d_in[0];
    const int*   ei  = (const int*)d_in[1];
    const float* W1l = (const float*)d_in[2];
    const float* b1  = (const float*)d_in[3];
    const float* W1r = (const float*)d_in[4];
    const float* W2l = (const float*)d_in[5];
    const float* b2  = (const float*)d_in[6];
    const float* W2r = (const float*)d_in[7];
    float* out = (float*)d_out;

    const int n = in_sizes[0] / D;   // 100000
    const int E = in_sizes[1] / 2;   // 1600000

    const size_t degB = (size_t)n * sizeof(float);
    const size_t o_agg = (degB + 255) & ~(size_t)255;
    const size_t featB = (size_t)n * D * sizeof(float);
    const size_t o_h   = o_agg + featB;

    char*  ws  = (char*)d_ws;
    float* deg = (float*)ws;
    float* agg = (float*)(ws + o_agg);
    float* h   = (float*)(ws + o_h);

    // zero deg + agg (layer 1)
    hipMemsetAsync(d_ws, 0, o_agg + featB, stream);

    const int aggThreads = E * 32;
    dim3 gAgg((aggThreads + 255) / 256);
    dim3 gLin((n + GROWS - 1) / GROWS);

    // layer 1
    k_agg<<<gAgg, 256, 0, stream>>>(x, ei, agg, deg, E, 1);
    k_linear<<<gLin, 256, 0, stream>>>(agg, deg, x, W1l, b1, W1r, h, n, 1);

    // layer 2
    hipMemsetAsync(agg, 0, featB, stream);
    k_agg<<<gAgg, 256, 0, stream>>>(h, ei, agg, deg, E, 0);
    k_linear<<<gLin, 256, 0, stream>>>(agg, deg, h, W2l, b2, W2r, out, n, 0);
}

// Round 6
// 682.556 us; speedup vs baseline: 8.4784x; 8.4784x over previous
//
// GraphSAGE MI355X — R6: resubmit of CSR kernel (R2–R5 all UnresponsiveContainer)
#include <hip/hip_runtime.h>

#define D 128

// ===========================================================================
// CSR build: count -> scan(3 kernels) -> scatter (row_ptr shift trick)
// ===========================================================================
__global__ __launch_bounds__(256) void k_count(const int* __restrict__ ei,
                                               int* __restrict__ cnt, int E)
{
    int e = blockIdx.x * 256 + threadIdx.x;
    if (e < E) atomicAdd(&cnt[ei[E + e]], 1);
}

__global__ __launch_bounds__(256) void k_bsum(const int* __restrict__ cnt,
                                              int* __restrict__ bsum, int n)
{
    __shared__ int s[256];
    int t = threadIdx.x;
    int i = blockIdx.x * 256 + t;
    s[t] = (i < n) ? cnt[i] : 0;
    __syncthreads();
    for (int o = 128; o > 0; o >>= 1) {
        if (t < o) s[t] += s[t + o];
        __syncthreads();
    }
    if (t == 0) bsum[blockIdx.x] = s[0];
}

// single-block exclusive scan of nb (<=512) block sums; also writes row_ptr[n]=E
__global__ __launch_bounds__(512) void k_scanb(int* __restrict__ bsum, int nb,
                                               int* __restrict__ row_ptr, int n, int E)
{
    __shared__ int s[512];
    int t = threadIdx.x;
    int v = (t < nb) ? bsum[t] : 0;
    s[t] = v;
    __syncthreads();
    for (int o = 1; o < 512; o <<= 1) {
        int add = (t >= o) ? s[t - o] : 0;
        __syncthreads();
        s[t] += add;
        __syncthreads();
    }
    if (t < nb) bsum[t] = s[t] - v;   // exclusive
    if (t == 0) row_ptr[n] = E;
}

__global__ __launch_bounds__(256) void k_scanfinal(const int* __restrict__ cnt,
                                                   const int* __restrict__ bsum,
                                                   int* __restrict__ row_ptr, int n)
{
    __shared__ int s[256];
    int t = threadIdx.x;
    int i = blockIdx.x * 256 + t;
    int v = (i < n) ? cnt[i] : 0;
    s[t] = v;
    __syncthreads();
    for (int o = 1; o < 256; o <<= 1) {
        int add = (t >= o) ? s[t - o] : 0;
        __syncthreads();
        s[t] += add;
        __syncthreads();
    }
    if (i < n) row_ptr[i] = s[t] - v + bsum[blockIdx.x];
}

// claims slots via atomicAdd on row_ptr; afterwards row_ptr[v] == start of v+1
__global__ __launch_bounds__(256) void k_scatter(const int* __restrict__ ei,
                                                 int* __restrict__ row_ptr,
                                                 int* __restrict__ csr_src, int E)
{
    int e = blockIdx.x * 256 + threadIdx.x;
    if (e >= E) return;
    int src = ei[e];
    int dst = ei[E + e];
    int pos = atomicAdd(&row_ptr[dst], 1);
    csr_src[pos] = src;
}

// ===========================================================================
// Aggregation: one wave (64 lanes) per dst node; float2 per lane (D=128).
// row_ptr is the post-scatter (shifted) array: beg = rp[v-1], end = rp[v].
// Writes the MEAN directly.
// ===========================================================================
__global__ __launch_bounds__(256) void k_agg_csr(const float* __restrict__ feat,
                                                 const int* __restrict__ row_ptr,
                                                 const int* __restrict__ csr_src,
                                                 float* __restrict__ mean, int n)
{
    int gtid = blockIdx.x * 256 + threadIdx.x;
    int v    = gtid >> 6;
    int lane = threadIdx.x & 63;
    if (v >= n) return;
    int beg = (v == 0) ? 0 : row_ptr[v - 1];
    int end = row_ptr[v];

    const float* fp = feat + lane * 2;
    float ax = 0.f, ay = 0.f;
    for (int base = beg; base < end; base += 64) {
        int m  = min(64, end - base);
        int id = (base + lane < end) ? csr_src[base + lane] : 0;
        int j = 0;
        for (; j + 4 <= m; j += 4) {
            int s0 = __shfl(id, j + 0);
            int s1 = __shfl(id, j + 1);
            int s2 = __shfl(id, j + 2);
            int s3 = __shfl(id, j + 3);
            float2 v0 = *(const float2*)(fp + (size_t)s0 * D);
            float2 v1 = *(const float2*)(fp + (size_t)s1 * D);
            float2 v2 = *(const float2*)(fp + (size_t)s2 * D);
            float2 v3 = *(const float2*)(fp + (size_t)s3 * D);
            ax += (v0.x + v1.x) + (v2.x + v3.x);
            ay += (v0.y + v1.y) + (v2.y + v3.y);
        }
        for (; j < m; j++) {
            int s = __shfl(id, j);
            float2 vv = *(const float2*)(fp + (size_t)s * D);
            ax += vv.x;
            ay += vv.y;
        }
    }
    float dinv = 1.0f / fmaxf((float)(end - beg), 1.0f);
    float2 o = make_float2(ax * dinv, ay * dinv);
    *(float2*)(mean + (size_t)v * D + lane * 2) = o;
}

// ===========================================================================
// Fused SAGE linear: out[r] = relu?( mean[r] @ Wl + b + xin[r] @ Wr )
// 256 threads, 32 rows/block. Safe when out == xin (block touches own rows;
// all global reads precede all global writes).
// ===========================================================================
#define GROWS 32
__global__ __launch_bounds__(256) void k_linear(const float* __restrict__ mean,
                                                const float* __restrict__ xin,
                                                const float* __restrict__ Wl,
                                                const float* __restrict__ bias,
                                                const float* __restrict__ Wr,
                                                float* __restrict__ out,
                                                int n, int relu)
{
    __shared__ float rows[GROWS][2 * D];   // 32 KB
    __shared__ float wbuf[64][D];          // 32 KB
    const int t  = threadIdx.x;
    const int r0 = blockIdx.x * GROWS;

    for (int f = t; f < GROWS * (2 * D / 4); f += 256) {
        int r  = f >> 6;
        int cc = (f & 63) * 4;
        int row = r0 + r;
        float4 v = make_float4(0.f, 0.f, 0.f, 0.f);
        if (row < n) {
            if (cc < D) v = *(const float4*)(mean + (size_t)row * D + cc);
            else        v = *(const float4*)(xin  + (size_t)row * D + (cc - D));
        }
        *(float4*)&rows[r][cc] = v;
    }

    const int j  = (t & 31) * 4;
    const int rt = t >> 5;
    float acc[4][4];
    #pragma unroll
    for (int a = 0; a < 4; a++)
        #pragma unroll
        for (int b = 0; b < 4; b++) acc[a][b] = 0.f;

    for (int kb = 0; kb < 2 * D; kb += 64) {
        __syncthreads();
        for (int f = t; f < 64 * (D / 4); f += 256) {
            int kk = f >> 5;
            int cc = (f & 31) * 4;
            int kg = kb + kk;
            const float* ws = (kg < D) ? (Wl + (size_t)kg * D + cc)
                                       : (Wr + (size_t)(kg - D) * D + cc);
            *(float4*)&wbuf[kk][cc] = *(const float4*)ws;
        }
        __syncthreads();
        #pragma unroll 8
        for (int kk = 0; kk < 64; kk++) {
            float4 w = *(const float4*)&wbuf[kk][j];
            int k = kb + kk;
            #pragma unroll
            for (int ri = 0; ri < 4; ri++) {
                float rv = rows[rt + ri * 8][k];
                acc[ri][0] += rv * w.x;
                acc[ri][1] += rv * w.y;
                acc[ri][2] += rv * w.z;
                acc[ri][3] += rv * w.w;
            }
        }
    }

    float4 bv = *(const float4*)(bias + j);
    #pragma unroll
    for (int ri = 0; ri < 4; ri++) {
        int row = r0 + rt + ri * 8;
        if (row >= n) continue;
        float4 o;
        o.x = acc[ri][0] + bv.x;
        o.y = acc[ri][1] + bv.y;
        o.z = acc[ri][2] + bv.z;
        o.w = acc[ri][3] + bv.w;
        if (relu) {
            o.x = fmaxf(o.x, 0.f); o.y = fmaxf(o.y, 0.f);
            o.z = fmaxf(o.z, 0.f); o.w = fmaxf(o.w, 0.f);
        }
        *(float4*)(out + (size_t)row * D + j) = o;
    }
}

extern "C" void kernel_launch(void* const* d_in, const int* in_sizes, int n_in,
                              void* d_out, int out_size, void* d_ws, size_t ws_size,
                              hipStream_t stream)
{
    const float* x   = (const float*)d_in[0];
    const int*   ei  = (const int*)d_in[1];
    const float* W1l = (const float*)d_in[2];
    const float* b1  = (const float*)d_in[3];
    const float* W1r = (const float*)d_in[4];
    const float* W2l = (const float*)d_in[5];
    const float* b2  = (const float*)d_in[6];
    const float* W2r = (const float*)d_in[7];
    float* out = (float*)d_out;

    const int n = in_sizes[0] / D;   // 100000
    const int E = in_sizes[1] / 2;   // 1600000
    const int nb = (n + 255) / 256;  // 391

    // workspace layout (~58.4 MB total; round-1 kernel used ~102 MB OK)
    size_t off = 0;
    auto alloc = [&](size_t bytes) { size_t o = off; off += (bytes + 511) & ~(size_t)511; return o; };
    char* ws = (char*)d_ws;
    int*   cnt     = (int*)(ws + alloc((size_t)n * 4));
    int*   bsum    = (int*)(ws + alloc((size_t)512 * 4));
    int*   row_ptr = (int*)(ws + alloc((size_t)(n + 1) * 4));
    int*   csr_src = (int*)(ws + alloc((size_t)E * 4));
    float* mean    = (float*)(ws + alloc((size_t)n * D * 4));
    float* h       = out;            // alias layer-1 output into d_out

    hipMemsetAsync(cnt, 0, (size_t)n * 4, stream);

    dim3 gE((E + 255) / 256), gN(nb);
    // CSR build (reused by both layers)
    k_count    <<<gE, 256, 0, stream>>>(ei, cnt, E);
    k_bsum     <<<gN, 256, 0, stream>>>(cnt, bsum, n);
    k_scanb    <<<1, 512, 0, stream>>>(bsum, nb, row_ptr, n, E);
    k_scanfinal<<<gN, 256, 0, stream>>>(cnt, bsum, row_ptr, n);
    k_scatter  <<<gE, 256, 0, stream>>>(ei, row_ptr, csr_src, E);

    dim3 gAggBlocks((n + 3) / 4);
    dim3 gLin((n + GROWS - 1) / GROWS);

    // layer 1
    k_agg_csr<<<gAggBlocks, 256, 0, stream>>>(x, row_ptr, csr_src, mean, n);
    k_linear <<<gLin, 256, 0, stream>>>(mean, x, W1l, b1, W1r, h, n, 1);

    // layer 2
    k_agg_csr<<<gAggBlocks, 256, 0, stream>>>(h, row_ptr, csr_src, mean, n);
    k_linear <<<gLin, 256, 0, stream>>>(mean, h, W2l, b2, W2r, out, n, 0);
}

// Round 8
// 522.018 us; speedup vs baseline: 11.0858x; 1.3075x over previous
//
// GraphSAGE MI355X — R8: resubmit of R7 bf16-MFMA kernel (R7 hit dead container)
#include <hip/hip_runtime.h>

#define D 128

typedef __attribute__((ext_vector_type(4))) float f32x4;
typedef __attribute__((ext_vector_type(8))) short bf16x8;
typedef unsigned short ushort_t;
typedef unsigned int uint_t;

__device__ inline ushort_t f2b(float f) {   // fp32 -> bf16 RNE
    uint_t u = __float_as_uint(f);
    u += 0x7FFF + ((u >> 16) & 1);
    return (ushort_t)(u >> 16);
}

// ===========================================================================
// CSR build: count -> scan(3 kernels) -> scatter (row_ptr shift trick)
// ===========================================================================
__global__ __launch_bounds__(256) void k_count(const int* __restrict__ ei,
                                               int* __restrict__ cnt, int E)
{
    int e = blockIdx.x * 256 + threadIdx.x;
    if (e < E) atomicAdd(&cnt[ei[E + e]], 1);
}

__global__ __launch_bounds__(256) void k_bsum(const int* __restrict__ cnt,
                                              int* __restrict__ bsum, int n)
{
    __shared__ int s[256];
    int t = threadIdx.x;
    int i = blockIdx.x * 256 + t;
    s[t] = (i < n) ? cnt[i] : 0;
    __syncthreads();
    for (int o = 128; o > 0; o >>= 1) {
        if (t < o) s[t] += s[t + o];
        __syncthreads();
    }
    if (t == 0) bsum[blockIdx.x] = s[0];
}

__global__ __launch_bounds__(512) void k_scanb(int* __restrict__ bsum, int nb,
                                               int* __restrict__ row_ptr, int n, int E)
{
    __shared__ int s[512];
    int t = threadIdx.x;
    int v = (t < nb) ? bsum[t] : 0;
    s[t] = v;
    __syncthreads();
    for (int o = 1; o < 512; o <<= 1) {
        int add = (t >= o) ? s[t - o] : 0;
        __syncthreads();
        s[t] += add;
        __syncthreads();
    }
    if (t < nb) bsum[t] = s[t] - v;   // exclusive
    if (t == 0) row_ptr[n] = E;
}

__global__ __launch_bounds__(256) void k_scanfinal(const int* __restrict__ cnt,
                                                   const int* __restrict__ bsum,
                                                   int* __restrict__ row_ptr, int n)
{
    __shared__ int s[256];
    int t = threadIdx.x;
    int i = blockIdx.x * 256 + t;
    int v = (i < n) ? cnt[i] : 0;
    s[t] = v;
    __syncthreads();
    for (int o = 1; o < 256; o <<= 1) {
        int add = (t >= o) ? s[t - o] : 0;
        __syncthreads();
        s[t] += add;
        __syncthreads();
    }
    if (i < n) row_ptr[i] = s[t] - v + bsum[blockIdx.x];
}

__global__ __launch_bounds__(256) void k_scatter(const int* __restrict__ ei,
                                                 int* __restrict__ row_ptr,
                                                 int* __restrict__ csr_src, int E)
{
    int e = blockIdx.x * 256 + threadIdx.x;
    if (e >= E) return;
    int src = ei[e];
    int dst = ei[E + e];
    int pos = atomicAdd(&row_ptr[dst], 1);
    csr_src[pos] = src;
}

// ===========================================================================
// one-time casts: x -> bf16; weights -> transposed bf16 Wt[col][k] (k=0..255,
// stacked [Wl;Wr]) for both layers
// ===========================================================================
__global__ __launch_bounds__(256) void k_cast_x(const float* __restrict__ x,
                                                ushort_t* __restrict__ xb, int total8)
{
    int i = blockIdx.x * 256 + threadIdx.x;   // one thread = 8 elems
    if (i >= total8) return;
    const float4* p = (const float4*)(x + (size_t)i * 8);
    float4 a = p[0], b = p[1];
    ushort_t o[8] = { f2b(a.x), f2b(a.y), f2b(a.z), f2b(a.w),
                      f2b(b.x), f2b(b.y), f2b(b.z), f2b(b.w) };
    *(ulonglong2*)(xb + (size_t)i * 8) = *(ulonglong2*)o;
}

__global__ __launch_bounds__(256) void k_prep_w(const float* __restrict__ W1l,
                                                const float* __restrict__ W1r,
                                                const float* __restrict__ W2l,
                                                const float* __restrict__ W2r,
                                                ushort_t* __restrict__ Wt1,
                                                ushort_t* __restrict__ Wt2)
{
    int idx = blockIdx.x * 256 + threadIdx.x;   // 128 cols * 256 k
    if (idx >= 128 * 256) return;
    int c = idx >> 8, k = idx & 255;
    float v1 = (k < D) ? W1l[(size_t)k * D + c] : W1r[(size_t)(k - D) * D + c];
    float v2 = (k < D) ? W2l[(size_t)k * D + c] : W2r[(size_t)(k - D) * D + c];
    Wt1[idx] = f2b(v1);
    Wt2[idx] = f2b(v2);
}

// ===========================================================================
// Aggregation: one wave per dst node; fp32 gather, fp32 accum, bf16 store.
// ===========================================================================
__global__ __launch_bounds__(256) void k_agg_csr(const float* __restrict__ feat,
                                                 const int* __restrict__ row_ptr,
                                                 const int* __restrict__ csr_src,
                                                 ushort_t* __restrict__ meanb, int n)
{
    int gtid = blockIdx.x * 256 + threadIdx.x;
    int v    = gtid >> 6;
    int lane = threadIdx.x & 63;
    if (v >= n) return;
    int beg = (v == 0) ? 0 : row_ptr[v - 1];
    int end = row_ptr[v];

    const float* fp = feat + lane * 2;
    float ax = 0.f, ay = 0.f;
    for (int base = beg; base < end; base += 64) {
        int m  = min(64, end - base);
        int id = (base + lane < end) ? csr_src[base + lane] : 0;
        int j = 0;
        for (; j + 4 <= m; j += 4) {
            int s0 = __shfl(id, j + 0);
            int s1 = __shfl(id, j + 1);
            int s2 = __shfl(id, j + 2);
            int s3 = __shfl(id, j + 3);
            float2 v0 = *(const float2*)(fp + (size_t)s0 * D);
            float2 v1 = *(const float2*)(fp + (size_t)s1 * D);
            float2 v2 = *(const float2*)(fp + (size_t)s2 * D);
            float2 v3 = *(const float2*)(fp + (size_t)s3 * D);
            ax += (v0.x + v1.x) + (v2.x + v3.x);
            ay += (v0.y + v1.y) + (v2.y + v3.y);
        }
        for (; j < m; j++) {
            int s = __shfl(id, j);
            float2 vv = *(const float2*)(fp + (size_t)s * D);
            ax += vv.x;
            ay += vv.y;
        }
    }
    float dinv = 1.0f / fmaxf((float)(end - beg), 1.0f);
    ushort_t o[2] = { f2b(ax * dinv), f2b(ay * dinv) };
    *(uint_t*)(meanb + (size_t)v * D + lane * 2) = *(uint_t*)o;
}

// ===========================================================================
// MFMA linear: out[r] = relu?( mean[r]@Wl + b + xin[r]@Wr ), K=256 via
// stacked bf16 A=[mean||x] and Wt[col][k]. LDS-free: A frags and B frags
// loaded directly from global (Wt is 64KB -> L2-resident).
// Block: 256 thr = 4 waves; wave handles 32 rows x 128 cols (2 A-sets/B).
// Frag layouts (16x16x32): A: lane holds A[l&15][(l>>4)*8+e]; B: lane holds
// B[(l>>4)*8+e][l&15]; C: reg j -> row (l>>4)*4+j, col l&15.
// ===========================================================================
__global__ __launch_bounds__(256) void k_linear_mfma(const ushort_t* __restrict__ meanb,
                                                     const ushort_t* __restrict__ xinb,
                                                     const ushort_t* __restrict__ Wt,
                                                     const float* __restrict__ bias,
                                                     float* __restrict__ outf,
                                                     ushort_t* __restrict__ outb,
                                                     int n, int relu)
{
    const int wave  = threadIdx.x >> 6;
    const int lane  = threadIdx.x & 63;
    const int kgrp  = lane >> 4;            // 0..3
    const int rbase = blockIdx.x * 128 + wave * 32;
    const int row0  = rbase + (lane & 15);
    const int row1  = row0 + 16;

    bf16x8 a0[8], a1[8];
    {
        const ushort_t* m0 = meanb + (size_t)row0 * D + kgrp * 8;
        const ushort_t* x0 = xinb  + (size_t)row0 * D + kgrp * 8;
        const ushort_t* m1 = meanb + (size_t)row1 * D + kgrp * 8;
        const ushort_t* x1 = xinb  + (size_t)row1 * D + kgrp * 8;
        #pragma unroll
        for (int kk = 0; kk < 4; kk++) {
            a0[kk]     = *(const bf16x8*)(m0 + kk * 32);
            a0[kk + 4] = *(const bf16x8*)(x0 + kk * 32);
            a1[kk]     = *(const bf16x8*)(m1 + kk * 32);
            a1[kk + 4] = *(const bf16x8*)(x1 + kk * 32);
        }
    }

    #pragma unroll
    for (int cb = 0; cb < 8; cb++) {
        const int col = cb * 16 + (lane & 15);
        const ushort_t* wrow = Wt + (size_t)col * 256 + kgrp * 8;
        f32x4 acc0 = {0.f, 0.f, 0.f, 0.f};
        f32x4 acc1 = {0.f, 0.f, 0.f, 0.f};
        #pragma unroll
        for (int kk = 0; kk < 8; kk++) {
            bf16x8 b = *(const bf16x8*)(wrow + kk * 32);
            acc0 = __builtin_amdgcn_mfma_f32_16x16x32_bf16(a0[kk], b, acc0, 0, 0, 0);
            acc1 = __builtin_amdgcn_mfma_f32_16x16x32_bf16(a1[kk], b, acc1, 0, 0, 0);
        }
        const float bv = bias[col];
        #pragma unroll
        for (int j = 0; j < 4; j++) {
            int r0w = rbase + kgrp * 4 + j;
            if (r0w < n) {
                float v = acc0[j] + bv;
                if (relu) v = fmaxf(v, 0.f);
                outf[(size_t)r0w * D + col] = v;
                if (outb) outb[(size_t)r0w * D + col] = f2b(v);
            }
            int r1w = r0w + 16;
            if (r1w < n) {
                float v = acc1[j] + bv;
                if (relu) v = fmaxf(v, 0.f);
                outf[(size_t)r1w * D + col] = v;
                if (outb) outb[(size_t)r1w * D + col] = f2b(v);
            }
        }
    }
}

extern "C" void kernel_launch(void* const* d_in, const int* in_sizes, int n_in,
                              void* d_out, int out_size, void* d_ws, size_t ws_size,
                              hipStream_t stream)
{
    const float* x   = (const float*)d_in[0];
    const int*   ei  = (const int*)d_in[1];
    const float* W1l = (const float*)d_in[2];
    const float* b1  = (const float*)d_in[3];
    const float* W1r = (const float*)d_in[4];
    const float* W2l = (const float*)d_in[5];
    const float* b2  = (const float*)d_in[6];
    const float* W2r = (const float*)d_in[7];
    float* out = (float*)d_out;

    const int n = in_sizes[0] / D;   // 100000
    const int E = in_sizes[1] / 2;   // 1600000
    const int nb = (n + 255) / 256;  // 391
    const int lin_blocks = (n + 127) / 128;          // 782
    const int npad = lin_blocks * 128;               // 100096 (A-load padding)

    // workspace layout (~84 MB; 102 MB proven OK in R1)
    size_t off = 0;
    auto alloc = [&](size_t bytes) { size_t o = off; off += (bytes + 511) & ~(size_t)511; return o; };
    char* ws = (char*)d_ws;
    int*      cnt     = (int*)(ws + alloc((size_t)n * 4));
    int*      bsum    = (int*)(ws + alloc((size_t)512 * 4));
    int*      row_ptr = (int*)(ws + alloc((size_t)(n + 1) * 4));
    int*      csr_src = (int*)(ws + alloc((size_t)E * 4));
    ushort_t* meanb   = (ushort_t*)(ws + alloc((size_t)npad * D * 2));
    ushort_t* xb      = (ushort_t*)(ws + alloc((size_t)npad * D * 2));
    ushort_t* hb      = (ushort_t*)(ws + alloc((size_t)npad * D * 2));
    ushort_t* Wt1     = (ushort_t*)(ws + alloc((size_t)128 * 256 * 2));
    ushort_t* Wt2     = (ushort_t*)(ws + alloc((size_t)128 * 256 * 2));
    float*    h       = out;   // fp32 h aliases d_out (layer-2 linear reads only hb)

    hipMemsetAsync(cnt, 0, (size_t)n * 4, stream);

    dim3 gE((E + 255) / 256), gN(nb);
    // CSR build (reused by both layers)
    k_count    <<<gE, 256, 0, stream>>>(ei, cnt, E);
    k_bsum     <<<gN, 256, 0, stream>>>(cnt, bsum, n);
    k_scanb    <<<1, 512, 0, stream>>>(bsum, nb, row_ptr, n, E);
    k_scanfinal<<<gN, 256, 0, stream>>>(cnt, bsum, row_ptr, n);
    k_scatter  <<<gE, 256, 0, stream>>>(ei, row_ptr, csr_src, E);

    // one-time casts
    const int total8 = n * D / 8;
    k_cast_x<<<dim3((total8 + 255) / 256), 256, 0, stream>>>(x, xb, total8);
    k_prep_w<<<dim3(128), 256, 0, stream>>>(W1l, W1r, W2l, W2r, Wt1, Wt2);

    dim3 gAgg((n + 3) / 4);
    dim3 gLin(lin_blocks);

    // layer 1
    k_agg_csr   <<<gAgg, 256, 0, stream>>>(x, row_ptr, csr_src, meanb, n);
    k_linear_mfma<<<gLin, 256, 0, stream>>>(meanb, xb, Wt1, b1, h, hb, n, 1);

    // layer 2
    k_agg_csr   <<<gAgg, 256, 0, stream>>>(h, row_ptr, csr_src, meanb, n);
    k_linear_mfma<<<gLin, 256, 0, stream>>>(meanb, hb, Wt2, b2, out, (ushort_t*)nullptr, n, 0);
}

// Round 10
// 423.224 us; speedup vs baseline: 13.6735x; 1.2334x over previous
//
// GraphSAGE MI355X — R10: R9 agg fixed (wave-uniform shfl; branchless masking)
#include <hip/hip_runtime.h>

#define D 128

typedef __attribute__((ext_vector_type(4))) float f32x4;
typedef __attribute__((ext_vector_type(8))) short bf16x8;
typedef unsigned short ushort_t;
typedef unsigned int uint_t;

__device__ inline ushort_t f2b(float f) {   // fp32 -> bf16 RNE
    uint_t u = __float_as_uint(f);
    u += 0x7FFF + ((u >> 16) & 1);
    return (ushort_t)(u >> 16);
}

__device__ inline void acc_bf8(float* acc, uint4 d) {  // 8 bf16 (4 dwords) += into fp32[8]
    acc[0] += __uint_as_float(d.x << 16);
    acc[1] += __uint_as_float(d.x & 0xffff0000u);
    acc[2] += __uint_as_float(d.y << 16);
    acc[3] += __uint_as_float(d.y & 0xffff0000u);
    acc[4] += __uint_as_float(d.z << 16);
    acc[5] += __uint_as_float(d.z & 0xffff0000u);
    acc[6] += __uint_as_float(d.w << 16);
    acc[7] += __uint_as_float(d.w & 0xffff0000u);
}

// ===========================================================================
// CSR build: count -> scan(3 kernels) -> scatter (row_ptr shift trick)
// ===========================================================================
__global__ __launch_bounds__(256) void k_count(const int* __restrict__ ei,
                                               int* __restrict__ cnt, int E)
{
    int e = blockIdx.x * 256 + threadIdx.x;
    if (e < E) atomicAdd(&cnt[ei[E + e]], 1);
}

__global__ __launch_bounds__(256) void k_bsum(const int* __restrict__ cnt,
                                              int* __restrict__ bsum, int n)
{
    __shared__ int s[256];
    int t = threadIdx.x;
    int i = blockIdx.x * 256 + t;
    s[t] = (i < n) ? cnt[i] : 0;
    __syncthreads();
    for (int o = 128; o > 0; o >>= 1) {
        if (t < o) s[t] += s[t + o];
        __syncthreads();
    }
    if (t == 0) bsum[blockIdx.x] = s[0];
}

__global__ __launch_bounds__(512) void k_scanb(int* __restrict__ bsum, int nb,
                                               int* __restrict__ row_ptr, int n, int E)
{
    __shared__ int s[512];
    int t = threadIdx.x;
    int v = (t < nb) ? bsum[t] : 0;
    s[t] = v;
    __syncthreads();
    for (int o = 1; o < 512; o <<= 1) {
        int add = (t >= o) ? s[t - o] : 0;
        __syncthreads();
        s[t] += add;
        __syncthreads();
    }
    if (t < nb) bsum[t] = s[t] - v;   // exclusive
    if (t == 0) row_ptr[n] = E;
}

__global__ __launch_bounds__(256) void k_scanfinal(const int* __restrict__ cnt,
                                                   const int* __restrict__ bsum,
                                                   int* __restrict__ row_ptr, int n)
{
    __shared__ int s[256];
    int t = threadIdx.x;
    int i = blockIdx.x * 256 + t;
    int v = (i < n) ? cnt[i] : 0;
    s[t] = v;
    __syncthreads();
    for (int o = 1; o < 256; o <<= 1) {
        int add = (t >= o) ? s[t - o] : 0;
        __syncthreads();
        s[t] += add;
        __syncthreads();
    }
    if (i < n) row_ptr[i] = s[t] - v + bsum[blockIdx.x];
}

__global__ __launch_bounds__(256) void k_scatter(const int* __restrict__ ei,
                                                 int* __restrict__ row_ptr,
                                                 int* __restrict__ csr_src, int E)
{
    int e = blockIdx.x * 256 + threadIdx.x;
    if (e >= E) return;
    int src = ei[e];
    int dst = ei[E + e];
    int pos = atomicAdd(&row_ptr[dst], 1);
    csr_src[pos] = src;
}

// ===========================================================================
// one-time casts: x -> bf16; weights -> transposed bf16 Wt[col][k]
// ===========================================================================
__global__ __launch_bounds__(256) void k_cast_x(const float* __restrict__ x,
                                                ushort_t* __restrict__ xb, int total8)
{
    int i = blockIdx.x * 256 + threadIdx.x;   // one thread = 8 elems
    if (i >= total8) return;
    const float4* p = (const float4*)(x + (size_t)i * 8);
    float4 a = p[0], b = p[1];
    uint4 st;
    st.x = (uint_t)f2b(a.x) | ((uint_t)f2b(a.y) << 16);
    st.y = (uint_t)f2b(a.z) | ((uint_t)f2b(a.w) << 16);
    st.z = (uint_t)f2b(b.x) | ((uint_t)f2b(b.y) << 16);
    st.w = (uint_t)f2b(b.z) | ((uint_t)f2b(b.w) << 16);
    *(uint4*)(xb + (size_t)i * 8) = st;
}

__global__ __launch_bounds__(256) void k_prep_w(const float* __restrict__ W1l,
                                                const float* __restrict__ W1r,
                                                const float* __restrict__ W2l,
                                                const float* __restrict__ W2r,
                                                ushort_t* __restrict__ Wt1,
                                                ushort_t* __restrict__ Wt2)
{
    int idx = blockIdx.x * 256 + threadIdx.x;   // 128 cols * 256 k
    if (idx >= 128 * 256) return;
    int c = idx >> 8, k = idx & 255;
    float v1 = (k < D) ? W1l[(size_t)k * D + c] : W1r[(size_t)(k - D) * D + c];
    float v2 = (k < D) ? W2l[(size_t)k * D + c] : W2r[(size_t)(k - D) * D + c];
    Wt1[idx] = f2b(v1);
    Wt2[idx] = f2b(v2);
}

// ===========================================================================
// Aggregation: one wave per dst node, gathering bf16 rows (256 B each).
// 16 lanes cover a row (8 bf16 = 16 B/lane); 4 subwarps process edges
// jj ≡ sw (mod 4) -> 4x memory-level parallelism. ALL cross-lane ops are
// wave-uniform: steps = ceil(m/4) is identical for all 64 lanes, every lane
// executes every __shfl (src ≤ 63 always; ds_bpermute from exec-inactive
// lanes is undefined -- the R9 bug). Invalid steps are neutralized
// branchlessly: OOB lanes carry id=0 (row 0, in-bounds) and the payload is
// masked to +0.0 before accumulation.
// ===========================================================================
__global__ __launch_bounds__(256) void k_agg_csr(const ushort_t* __restrict__ featb,
                                                 const int* __restrict__ row_ptr,
                                                 const int* __restrict__ csr_src,
                                                 ushort_t* __restrict__ meanb, int n)
{
    int gtid = blockIdx.x * 256 + threadIdx.x;
    int v    = gtid >> 6;
    if (v >= n) return;
    int lane = threadIdx.x & 63;
    int sw   = lane >> 4;      // subwarp 0..3: edges ≡ sw (mod 4)
    int sl   = lane & 15;      // col group: cols sl*8 .. sl*8+7

    int beg = (v == 0) ? 0 : row_ptr[v - 1];
    int end = row_ptr[v];

    const ushort_t* fb = featb + sl * 8;
    float acc[8] = {0.f, 0.f, 0.f, 0.f, 0.f, 0.f, 0.f, 0.f};

    for (int base = beg; base < end; base += 64) {
        int m = end - base; if (m > 64) m = 64;          // wave-uniform
        int id = (base + lane < end) ? csr_src[base + lane] : 0;
        int steps = (m + 3) >> 2;                        // wave-uniform
        #pragma unroll 4
        for (int t = 0; t < steps; t++) {
            int jj = sw + 4 * t;                         // ≤ 63 always
            int s  = __shfl(id, jj);                     // all 64 lanes active
            uint4 r = *(const uint4*)(fb + (size_t)s * D);
            uint_t msk = (jj < m) ? 0xffffffffu : 0u;
            r.x &= msk; r.y &= msk; r.z &= msk; r.w &= msk;
            acc_bf8(acc, r);
        }
    }

    // reduce partials across the 4 subwarps (uniform; lanes l, l^16, l^32, l^48)
    #pragma unroll
    for (int q = 0; q < 8; q++) {
        acc[q] += __shfl_xor(acc[q], 16);
        acc[q] += __shfl_xor(acc[q], 32);
    }

    if (sw == 0) {
        float dinv = 1.0f / fmaxf((float)(end - beg), 1.0f);
        uint4 st;
        st.x = (uint_t)f2b(acc[0] * dinv) | ((uint_t)f2b(acc[1] * dinv) << 16);
        st.y = (uint_t)f2b(acc[2] * dinv) | ((uint_t)f2b(acc[3] * dinv) << 16);
        st.z = (uint_t)f2b(acc[4] * dinv) | ((uint_t)f2b(acc[5] * dinv) << 16);
        st.w = (uint_t)f2b(acc[6] * dinv) | ((uint_t)f2b(acc[7] * dinv) << 16);
        *(uint4*)(meanb + (size_t)v * D + sl * 8) = st;
    }
}

// ===========================================================================
// MFMA linear: out[r] = relu?( mean[r]@Wl + b + xin[r]@Wr ), K=256, LDS-free.
// outf (fp32) and outb (bf16) are each optional.
// ===========================================================================
__global__ __launch_bounds__(256) void k_linear_mfma(const ushort_t* __restrict__ meanb,
                                                     const ushort_t* __restrict__ xinb,
                                                     const ushort_t* __restrict__ Wt,
                                                     const float* __restrict__ bias,
                                                     float* __restrict__ outf,
                                                     ushort_t* __restrict__ outb,
                                                     int n, int relu)
{
    const int wave  = threadIdx.x >> 6;
    const int lane  = threadIdx.x & 63;
    const int kgrp  = lane >> 4;            // 0..3
    const int rbase = blockIdx.x * 128 + wave * 32;
    const int row0  = rbase + (lane & 15);
    const int row1  = row0 + 16;

    bf16x8 a0[8], a1[8];
    {
        const ushort_t* m0 = meanb + (size_t)row0 * D + kgrp * 8;
        const ushort_t* x0 = xinb  + (size_t)row0 * D + kgrp * 8;
        const ushort_t* m1 = meanb + (size_t)row1 * D + kgrp * 8;
        const ushort_t* x1 = xinb  + (size_t)row1 * D + kgrp * 8;
        #pragma unroll
        for (int kk = 0; kk < 4; kk++) {
            a0[kk]     = *(const bf16x8*)(m0 + kk * 32);
            a0[kk + 4] = *(const bf16x8*)(x0 + kk * 32);
            a1[kk]     = *(const bf16x8*)(m1 + kk * 32);
            a1[kk + 4] = *(const bf16x8*)(x1 + kk * 32);
        }
    }

    #pragma unroll
    for (int cb = 0; cb < 8; cb++) {
        const int col = cb * 16 + (lane & 15);
        const ushort_t* wrow = Wt + (size_t)col * 256 + kgrp * 8;
        f32x4 acc0 = {0.f, 0.f, 0.f, 0.f};
        f32x4 acc1 = {0.f, 0.f, 0.f, 0.f};
        #pragma unroll
        for (int kk = 0; kk < 8; kk++) {
            bf16x8 b = *(const bf16x8*)(wrow + kk * 32);
            acc0 = __builtin_amdgcn_mfma_f32_16x16x32_bf16(a0[kk], b, acc0, 0, 0, 0);
            acc1 = __builtin_amdgcn_mfma_f32_16x16x32_bf16(a1[kk], b, acc1, 0, 0, 0);
        }
        const float bv = bias[col];
        #pragma unroll
        for (int j = 0; j < 4; j++) {
            int r0w = rbase + kgrp * 4 + j;
            if (r0w < n) {
                float v = acc0[j] + bv;
                if (relu) v = fmaxf(v, 0.f);
                if (outf) outf[(size_t)r0w * D + col] = v;
                if (outb) outb[(size_t)r0w * D + col] = f2b(v);
            }
            int r1w = r0w + 16;
            if (r1w < n) {
                float v = acc1[j] + bv;
                if (relu) v = fmaxf(v, 0.f);
                if (outf) outf[(size_t)r1w * D + col] = v;
                if (outb) outb[(size_t)r1w * D + col] = f2b(v);
            }
        }
    }
}

extern "C" void kernel_launch(void* const* d_in, const int* in_sizes, int n_in,
                              void* d_out, int out_size, void* d_ws, size_t ws_size,
                              hipStream_t stream)
{
    const float* x   = (const float*)d_in[0];
    const int*   ei  = (const int*)d_in[1];
    const float* W1l = (const float*)d_in[2];
    const float* b1  = (const float*)d_in[3];
    const float* W1r = (const float*)d_in[4];
    const float* W2l = (const float*)d_in[5];
    const float* b2  = (const float*)d_in[6];
    const float* W2r = (const float*)d_in[7];
    float* out = (float*)d_out;

    const int n = in_sizes[0] / D;   // 100000
    const int E = in_sizes[1] / 2;   // 1600000
    const int nb = (n + 255) / 256;  // 391
    const int lin_blocks = (n + 127) / 128;          // 782
    const int npad = lin_blocks * 128;               // 100096 (A-load padding)

    // workspace layout (~84 MB; 102 MB proven OK in R1)
    size_t off = 0;
    auto alloc = [&](size_t bytes) { size_t o = off; off += (bytes + 511) & ~(size_t)511; return o; };
    char* ws = (char*)d_ws;
    int*      cnt     = (int*)(ws + alloc((size_t)n * 4));
    int*      bsum    = (int*)(ws + alloc((size_t)512 * 4));
    int*      row_ptr = (int*)(ws + alloc((size_t)(n + 1) * 4));
    int*      csr_src = (int*)(ws + alloc((size_t)E * 4));
    ushort_t* meanb   = (ushort_t*)(ws + alloc((size_t)npad * D * 2));
    ushort_t* xb      = (ushort_t*)(ws + alloc((size_t)npad * D * 2));
    ushort_t* hb      = (ushort_t*)(ws + alloc((size_t)npad * D * 2));
    ushort_t* Wt1     = (ushort_t*)(ws + alloc((size_t)128 * 256 * 2));
    ushort_t* Wt2     = (ushort_t*)(ws + alloc((size_t)128 * 256 * 2));

    hipMemsetAsync(cnt, 0, (size_t)n * 4, stream);

    dim3 gE((E + 255) / 256), gN(nb);
    // CSR build (reused by both layers)
    k_count    <<<gE, 256, 0, stream>>>(ei, cnt, E);
    k_bsum     <<<gN, 256, 0, stream>>>(cnt, bsum, n);
    k_scanb    <<<1, 512, 0, stream>>>(bsum, nb, row_ptr, n, E);
    k_scanfinal<<<gN, 256, 0, stream>>>(cnt, bsum, row_ptr, n);
    k_scatter  <<<gE, 256, 0, stream>>>(ei, row_ptr, csr_src, E);

    // one-time casts
    const int total8 = n * D / 8;
    k_cast_x<<<dim3((total8 + 255) / 256), 256, 0, stream>>>(x, xb, total8);
    k_prep_w<<<dim3(128), 256, 0, stream>>>(W1l, W1r, W2l, W2r, Wt1, Wt2);

    dim3 gAgg((n + 3) / 4);
    dim3 gLin(lin_blocks);

    // layer 1 (agg gathers bf16 x; linear emits bf16 h only)
    k_agg_csr    <<<gAgg, 256, 0, stream>>>(xb, row_ptr, csr_src, meanb, n);
    k_linear_mfma<<<gLin, 256, 0, stream>>>(meanb, xb, Wt1, b1, (float*)nullptr, hb, n, 1);

    // layer 2 (agg gathers bf16 h; linear writes fp32 out)
    k_agg_csr    <<<gAgg, 256, 0, stream>>>(hb, row_ptr, csr_src, meanb, n);
    k_linear_mfma<<<gLin, 256, 0, stream>>>(meanb, hb, Wt2, b2, out, (ushort_t*)nullptr, n, 0);
}

// Round 11
// 328.890 us; speedup vs baseline: 17.5954x; 1.2868x over previous
//
// GraphSAGE MI355X — R11: bucket-localized CSR build (binscatter + per-bucket fine scatter)
// replaces the 133 µs global-atomic scatter (106 MB write amplification)
#include <hip/hip_runtime.h>

#define D 128
#define NBK_MAX 512
#define EPB 4096   // edges per binscatter block

typedef __attribute__((ext_vector_type(4))) float f32x4;
typedef __attribute__((ext_vector_type(8))) short bf16x8;
typedef unsigned short ushort_t;
typedef unsigned int uint_t;
typedef unsigned long long u64_t;

__device__ inline ushort_t f2b(float f) {   // fp32 -> bf16 RNE
    uint_t u = __float_as_uint(f);
    u += 0x7FFF + ((u >> 16) & 1);
    return (ushort_t)(u >> 16);
}

__device__ inline void acc_bf8(float* acc, uint4 d) {  // 8 bf16 (4 dwords) += into fp32[8]
    acc[0] += __uint_as_float(d.x << 16);
    acc[1] += __uint_as_float(d.x & 0xffff0000u);
    acc[2] += __uint_as_float(d.y << 16);
    acc[3] += __uint_as_float(d.y & 0xffff0000u);
    acc[4] += __uint_as_float(d.z << 16);
    acc[5] += __uint_as_float(d.z & 0xffff0000u);
    acc[6] += __uint_as_float(d.w << 16);
    acc[7] += __uint_as_float(d.w & 0xffff0000u);
}

// ===========================================================================
// degree count + scan (row_ptr stays clean exclusive; bsum doubles as bucket
// bases for the binscatter: bsum[b] == row_ptr[b*256])
// ===========================================================================
__global__ __launch_bounds__(256) void k_count(const int* __restrict__ ei,
                                               int* __restrict__ cnt, int E)
{
    int e = blockIdx.x * 256 + threadIdx.x;
    if (e < E) atomicAdd(&cnt[ei[E + e]], 1);
}

__global__ __launch_bounds__(256) void k_bsum(const int* __restrict__ cnt,
                                              int* __restrict__ bsum, int n)
{
    __shared__ int s[256];
    int t = threadIdx.x;
    int i = blockIdx.x * 256 + t;
    s[t] = (i < n) ? cnt[i] : 0;
    __syncthreads();
    for (int o = 128; o > 0; o >>= 1) {
        if (t < o) s[t] += s[t + o];
        __syncthreads();
    }
    if (t == 0) bsum[blockIdx.x] = s[0];
}

// exclusive scan of nb (<=512) block sums; writes bsum (pristine) + fill
// (mutable cursor copy); also row_ptr[n] = E
__global__ __launch_bounds__(512) void k_scanb(int* __restrict__ bsum, int nb,
                                               int* __restrict__ fill,
                                               int* __restrict__ row_ptr, int n, int E)
{
    __shared__ int s[512];
    int t = threadIdx.x;
    int v = (t < nb) ? bsum[t] : 0;
    s[t] = v;
    __syncthreads();
    for (int o = 1; o < 512; o <<= 1) {
        int add = (t >= o) ? s[t - o] : 0;
        __syncthreads();
        s[t] += add;
        __syncthreads();
    }
    if (t < nb) {
        int ex = s[t] - v;   // exclusive
        bsum[t] = ex;
        fill[t] = ex;
    }
    if (t == 0) row_ptr[n] = E;
}

__global__ __launch_bounds__(256) void k_scanfinal(const int* __restrict__ cnt,
                                                   const int* __restrict__ bsum,
                                                   int* __restrict__ row_ptr, int n)
{
    __shared__ int s[256];
    int t = threadIdx.x;
    int i = blockIdx.x * 256 + t;
    int v = (i < n) ? cnt[i] : 0;
    s[t] = v;
    __syncthreads();
    for (int o = 1; o < 256; o <<= 1) {
        int add = (t >= o) ? s[t - o] : 0;
        __syncthreads();
        s[t] += add;
        __syncthreads();
    }
    if (i < n) row_ptr[i] = s[t] - v + bsum[blockIdx.x];
}

// ===========================================================================
// Stage 1: group edges by dst-bucket (256 nodes/bucket). Per-block LDS
// histogram -> per-edge rank; one global atomicAdd per (block,bucket) reserves
// a contiguous chunk; edges written as u64 {loc8 (<<32) | src}. Every eb
// cache line is written by exactly one block -> no cross-XCD partial-line
// writebacks (the R10 scatter's 16x amplification).
// ===========================================================================
__global__ __launch_bounds__(256) void k_binscatter(const int* __restrict__ ei,
                                                    int* __restrict__ fill,
                                                    u64_t* __restrict__ eb,
                                                    int E, int nbk)
{
    __shared__ int hist[NBK_MAX];
    __shared__ int gbase[NBK_MAX];
    const int t = threadIdx.x;
    const int e0 = blockIdx.x * EPB;

    for (int i = t; i < nbk; i += 256) hist[i] = 0;
    __syncthreads();

    int src[16], dst[16], rank[16];
    #pragma unroll
    for (int i = 0; i < 16; i++) {
        int e = e0 + i * 256 + t;
        bool ok = (e < E);
        src[i]  = ok ? ei[e] : 0;
        dst[i]  = ok ? ei[E + e] : -1;
        rank[i] = ok ? atomicAdd(&hist[dst[i] >> 8], 1) : 0;
    }
    __syncthreads();
    for (int b = t; b < nbk; b += 256) {
        int c = hist[b];
        gbase[b] = c ? atomicAdd(&fill[b], c) : 0;
    }
    __syncthreads();
    #pragma unroll
    for (int i = 0; i < 16; i++) {
        if (dst[i] >= 0) {
            int pos = gbase[dst[i] >> 8] + rank[i];
            eb[pos] = ((u64_t)(uint_t)(dst[i] & 255) << 32) | (uint_t)src[i];
        }
    }
}

// ===========================================================================
// Stage 2: one block per bucket; scatter src into the bucket's contiguous
// csr region (~16 KB, single-block-owned -> L2-local writes).
// ===========================================================================
__global__ __launch_bounds__(256) void k_csr_fine(const u64_t* __restrict__ eb,
                                                  const int* __restrict__ rp,
                                                  int* __restrict__ csr_src, int n)
{
    __shared__ int start[256];
    __shared__ int fl[256];
    const int b = blockIdx.x;
    const int t = threadIdx.x;
    const int node0 = b * 256;
    const int base = rp[node0];
    const int nend = min(node0 + 256, n);
    const int cntb = rp[nend] - base;

    int node = node0 + t;
    start[t] = (node < n) ? rp[node] - base : 0;
    fl[t] = 0;
    __syncthreads();

    for (int i = t; i < cntb; i += 256) {
        u64_t e = eb[base + i];
        int s   = (int)(uint_t)(e & 0xffffffffu);
        int loc = (int)(uint_t)(e >> 32);
        int off = start[loc] + atomicAdd(&fl[loc], 1);
        csr_src[base + off] = s;
    }
}

// ===========================================================================
// one-time casts: x -> bf16; weights -> transposed bf16 Wt[col][k]
// ===========================================================================
__global__ __launch_bounds__(256) void k_cast_x(const float* __restrict__ x,
                                                ushort_t* __restrict__ xb, int total8)
{
    int i = blockIdx.x * 256 + threadIdx.x;   // one thread = 8 elems
    if (i >= total8) return;
    const float4* p = (const float4*)(x + (size_t)i * 8);
    float4 a = p[0], b = p[1];
    uint4 st;
    st.x = (uint_t)f2b(a.x) | ((uint_t)f2b(a.y) << 16);
    st.y = (uint_t)f2b(a.z) | ((uint_t)f2b(a.w) << 16);
    st.z = (uint_t)f2b(b.x) | ((uint_t)f2b(b.y) << 16);
    st.w = (uint_t)f2b(b.z) | ((uint_t)f2b(b.w) << 16);
    *(uint4*)(xb + (size_t)i * 8) = st;
}

__global__ __launch_bounds__(256) void k_prep_w(const float* __restrict__ W1l,
                                                const float* __restrict__ W1r,
                                                const float* __restrict__ W2l,
                                                const float* __restrict__ W2r,
                                                ushort_t* __restrict__ Wt1,
                                                ushort_t* __restrict__ Wt2)
{
    int idx = blockIdx.x * 256 + threadIdx.x;   // 128 cols * 256 k
    if (idx >= 128 * 256) return;
    int c = idx >> 8, k = idx & 255;
    float v1 = (k < D) ? W1l[(size_t)k * D + c] : W1r[(size_t)(k - D) * D + c];
    float v2 = (k < D) ? W2l[(size_t)k * D + c] : W2r[(size_t)(k - D) * D + c];
    Wt1[idx] = f2b(v1);
    Wt2[idx] = f2b(v2);
}

// ===========================================================================
// Aggregation: one wave per dst node, bf16 gather (256 B rows, 16 lanes/row,
// 4 subwarps -> 4 edges in flight). All cross-lane ops wave-uniform;
// OOB steps neutralized branchlessly (id=0 row + zero mask).
// row_ptr is clean exclusive: beg=rp[v], end=rp[v+1].
// ===========================================================================
__global__ __launch_bounds__(256) void k_agg_csr(const ushort_t* __restrict__ featb,
                                                 const int* __restrict__ row_ptr,
                                                 const int* __restrict__ csr_src,
                                                 ushort_t* __restrict__ meanb, int n)
{
    int gtid = blockIdx.x * 256 + threadIdx.x;
    int v    = gtid >> 6;
    if (v >= n) return;
    int lane = threadIdx.x & 63;
    int sw   = lane >> 4;
    int sl   = lane & 15;

    int beg = row_ptr[v];
    int end = row_ptr[v + 1];

    const ushort_t* fb = featb + sl * 8;
    float acc[8] = {0.f, 0.f, 0.f, 0.f, 0.f, 0.f, 0.f, 0.f};

    for (int base = beg; base < end; base += 64) {
        int m = end - base; if (m > 64) m = 64;          // wave-uniform
        int id = (base + lane < end) ? csr_src[base + lane] : 0;
        int steps = (m + 3) >> 2;                        // wave-uniform
        #pragma unroll 4
        for (int t = 0; t < steps; t++) {
            int jj = sw + 4 * t;                         // <= 63 always
            int s  = __shfl(id, jj);                     // all 64 lanes active
            uint4 r = *(const uint4*)(fb + (size_t)s * D);
            uint_t msk = (jj < m) ? 0xffffffffu : 0u;
            r.x &= msk; r.y &= msk; r.z &= msk; r.w &= msk;
            acc_bf8(acc, r);
        }
    }

    #pragma unroll
    for (int q = 0; q < 8; q++) {
        acc[q] += __shfl_xor(acc[q], 16);
        acc[q] += __shfl_xor(acc[q], 32);
    }

    if (sw == 0) {
        float dinv = 1.0f / fmaxf((float)(end - beg), 1.0f);
        uint4 st;
        st.x = (uint_t)f2b(acc[0] * dinv) | ((uint_t)f2b(acc[1] * dinv) << 16);
        st.y = (uint_t)f2b(acc[2] * dinv) | ((uint_t)f2b(acc[3] * dinv) << 16);
        st.z = (uint_t)f2b(acc[4] * dinv) | ((uint_t)f2b(acc[5] * dinv) << 16);
        st.w = (uint_t)f2b(acc[6] * dinv) | ((uint_t)f2b(acc[7] * dinv) << 16);
        *(uint4*)(meanb + (size_t)v * D + sl * 8) = st;
    }
}

// ===========================================================================
// MFMA linear: out[r] = relu?( mean[r]@Wl + b + xin[r]@Wr ), K=256, LDS-free.
// ===========================================================================
__global__ __launch_bounds__(256) void k_linear_mfma(const ushort_t* __restrict__ meanb,
                                                     const ushort_t* __restrict__ xinb,
                                                     const ushort_t* __restrict__ Wt,
                                                     const float* __restrict__ bias,
                                                     float* __restrict__ outf,
                                                     ushort_t* __restrict__ outb,
                                                     int n, int relu)
{
    const int wave  = threadIdx.x >> 6;
    const int lane  = threadIdx.x & 63;
    const int kgrp  = lane >> 4;            // 0..3
    const int rbase = blockIdx.x * 128 + wave * 32;
    const int row0  = rbase + (lane & 15);
    const int row1  = row0 + 16;

    bf16x8 a0[8], a1[8];
    {
        const ushort_t* m0 = meanb + (size_t)row0 * D + kgrp * 8;
        const ushort_t* x0 = xinb  + (size_t)row0 * D + kgrp * 8;
        const ushort_t* m1 = meanb + (size_t)row1 * D + kgrp * 8;
        const ushort_t* x1 = xinb  + (size_t)row1 * D + kgrp * 8;
        #pragma unroll
        for (int kk = 0; kk < 4; kk++) {
            a0[kk]     = *(const bf16x8*)(m0 + kk * 32);
            a0[kk + 4] = *(const bf16x8*)(x0 + kk * 32);
            a1[kk]     = *(const bf16x8*)(m1 + kk * 32);
            a1[kk + 4] = *(const bf16x8*)(x1 + kk * 32);
        }
    }

    #pragma unroll
    for (int cb = 0; cb < 8; cb++) {
        const int col = cb * 16 + (lane & 15);
        const ushort_t* wrow = Wt + (size_t)col * 256 + kgrp * 8;
        f32x4 acc0 = {0.f, 0.f, 0.f, 0.f};
        f32x4 acc1 = {0.f, 0.f, 0.f, 0.f};
        #pragma unroll
        for (int kk = 0; kk < 8; kk++) {
            bf16x8 b = *(const bf16x8*)(wrow + kk * 32);
            acc0 = __builtin_amdgcn_mfma_f32_16x16x32_bf16(a0[kk], b, acc0, 0, 0, 0);
            acc1 = __builtin_amdgcn_mfma_f32_16x16x32_bf16(a1[kk], b, acc1, 0, 0, 0);
        }
        const float bv = bias[col];
        #pragma unroll
        for (int j = 0; j < 4; j++) {
            int r0w = rbase + kgrp * 4 + j;
            if (r0w < n) {
                float v = acc0[j] + bv;
                if (relu) v = fmaxf(v, 0.f);
                if (outf) outf[(size_t)r0w * D + col] = v;
                if (outb) outb[(size_t)r0w * D + col] = f2b(v);
            }
            int r1w = r0w + 16;
            if (r1w < n) {
                float v = acc1[j] + bv;
                if (relu) v = fmaxf(v, 0.f);
                if (outf) outf[(size_t)r1w * D + col] = v;
                if (outb) outb[(size_t)r1w * D + col] = f2b(v);
            }
        }
    }
}

extern "C" void kernel_launch(void* const* d_in, const int* in_sizes, int n_in,
                              void* d_out, int out_size, void* d_ws, size_t ws_size,
                              hipStream_t stream)
{
    const float* x   = (const float*)d_in[0];
    const int*   ei  = (const int*)d_in[1];
    const float* W1l = (const float*)d_in[2];
    const float* b1  = (const float*)d_in[3];
    const float* W1r = (const float*)d_in[4];
    const float* W2l = (const float*)d_in[5];
    const float* b2  = (const float*)d_in[6];
    const float* W2r = (const float*)d_in[7];
    float* out = (float*)d_out;

    const int n = in_sizes[0] / D;   // 100000
    const int E = in_sizes[1] / 2;   // 1600000
    const int nbk = (n + 255) / 256; // 391 buckets == scan blocks
    const int lin_blocks = (n + 127) / 128;          // 782
    const int npad = lin_blocks * 128;               // 100096

    // workspace layout (~97 MB; 102 MB proven OK in R1)
    size_t off = 0;
    auto alloc = [&](size_t bytes) { size_t o = off; off += (bytes + 511) & ~(size_t)511; return o; };
    char* ws = (char*)d_ws;
    int*      cnt     = (int*)(ws + alloc((size_t)n * 4));
    int*      bsum    = (int*)(ws + alloc((size_t)512 * 4));
    int*      fill    = (int*)(ws + alloc((size_t)512 * 4));
    int*      row_ptr = (int*)(ws + alloc((size_t)(n + 1) * 4));
    u64_t*    eb      = (u64_t*)(ws + alloc((size_t)E * 8));
    int*      csr_src = (int*)(ws + alloc((size_t)E * 4));
    ushort_t* meanb   = (ushort_t*)(ws + alloc((size_t)npad * D * 2));
    ushort_t* xb      = (ushort_t*)(ws + alloc((size_t)npad * D * 2));
    ushort_t* hb      = (ushort_t*)(ws + alloc((size_t)npad * D * 2));
    ushort_t* Wt1     = (ushort_t*)(ws + alloc((size_t)128 * 256 * 2));
    ushort_t* Wt2     = (ushort_t*)(ws + alloc((size_t)128 * 256 * 2));

    hipMemsetAsync(cnt, 0, (size_t)n * 4, stream);

    dim3 gE((E + 255) / 256), gN(nbk);
    // CSR build (reused by both layers)
    k_count     <<<gE, 256, 0, stream>>>(ei, cnt, E);
    k_bsum      <<<gN, 256, 0, stream>>>(cnt, bsum, n);
    k_scanb     <<<1, 512, 0, stream>>>(bsum, nbk, fill, row_ptr, n, E);
    k_scanfinal <<<gN, 256, 0, stream>>>(cnt, bsum, row_ptr, n);
    k_binscatter<<<dim3((E + EPB - 1) / EPB), 256, 0, stream>>>(ei, fill, eb, E, nbk);
    k_csr_fine  <<<gN, 256, 0, stream>>>(eb, row_ptr, csr_src, n);

    // one-time casts
    const int total8 = n * D / 8;
    k_cast_x<<<dim3((total8 + 255) / 256), 256, 0, stream>>>(x, xb, total8);
    k_prep_w<<<dim3(128), 256, 0, stream>>>(W1l, W1r, W2l, W2r, Wt1, Wt2);

    dim3 gAgg((n + 3) / 4);
    dim3 gLin(lin_blocks);

    // layer 1 (agg gathers bf16 x; linear emits bf16 h only)
    k_agg_csr    <<<gAgg, 256, 0, stream>>>(xb, row_ptr, csr_src, meanb, n);
    k_linear_mfma<<<gLin, 256, 0, stream>>>(meanb, xb, Wt1, b1, (float*)nullptr, hb, n, 1);

    // layer 2 (agg gathers bf16 h; linear writes fp32 out)
    k_agg_csr    <<<gAgg, 256, 0, stream>>>(hb, row_ptr, csr_src, meanb, n);
    k_linear_mfma<<<gLin, 256, 0, stream>>>(meanb, hb, Wt2, b2, out, (ushort_t*)nullptr, n, 0);
}

// Round 12
// 273.111 us; speedup vs baseline: 21.1891x; 1.2042x over previous
//
// GraphSAGE MI355X — R12: node-count kernels deleted; row_ptr built inside the
// bucket pipeline (bucket_count -> scan -> binscatter(u32) -> csr_fine+row_ptr)
#include <hip/hip_runtime.h>

#define D 128
#define NBK_MAX 512
#define EPB 4096   // edges per bucket-count / binscatter block

typedef __attribute__((ext_vector_type(4))) float f32x4;
typedef __attribute__((ext_vector_type(8))) short bf16x8;
typedef unsigned short ushort_t;
typedef unsigned int uint_t;

__device__ inline ushort_t f2b(float f) {   // fp32 -> bf16 RNE
    uint_t u = __float_as_uint(f);
    u += 0x7FFF + ((u >> 16) & 1);
    return (ushort_t)(u >> 16);
}

__device__ inline void acc_bf8(float* acc, uint4 d) {  // 8 bf16 (4 dwords) += into fp32[8]
    acc[0] += __uint_as_float(d.x << 16);
    acc[1] += __uint_as_float(d.x & 0xffff0000u);
    acc[2] += __uint_as_float(d.y << 16);
    acc[3] += __uint_as_float(d.y & 0xffff0000u);
    acc[4] += __uint_as_float(d.z << 16);
    acc[5] += __uint_as_float(d.z & 0xffff0000u);
    acc[6] += __uint_as_float(d.w << 16);
    acc[7] += __uint_as_float(d.w & 0xffff0000u);
}

// ===========================================================================
// Stage 0: per-bucket edge counts. LDS histogram per 4096-edge chunk, then
// one global atomicAdd per (block,bucket): 391*391 low-contention atomics
// (replaces 1.6M per-node atomics of the old k_count, 65 us).
// ===========================================================================
__global__ __launch_bounds__(256) void k_bucket_count(const int* __restrict__ ei,
                                                      int* __restrict__ bcnt,
                                                      int E, int nbk)
{
    __shared__ int hist[NBK_MAX];
    const int t = threadIdx.x;
    const int e0 = blockIdx.x * EPB;
    for (int i = t; i < nbk; i += 256) hist[i] = 0;
    __syncthreads();
    #pragma unroll
    for (int i = 0; i < 16; i++) {
        int e = e0 + i * 256 + t;
        if (e < E) atomicAdd(&hist[ei[E + e] >> 8], 1);
    }
    __syncthreads();
    for (int b = t; b < nbk; b += 256) {
        int c = hist[b];
        if (c) atomicAdd(&bcnt[b], c);
    }
}

// exclusive scan of nbk (<=512) bucket counts -> bbase (pristine, with
// bbase[nbk]=E) and fill (mutable cursors); also row_ptr[n]=E
__global__ __launch_bounds__(512) void k_scanb(const int* __restrict__ bcnt, int nbk,
                                               int* __restrict__ bbase,
                                               int* __restrict__ fill,
                                               int* __restrict__ row_ptr, int n, int E)
{
    __shared__ int s[512];
    int t = threadIdx.x;
    int v = (t < nbk) ? bcnt[t] : 0;
    s[t] = v;
    __syncthreads();
    for (int o = 1; o < 512; o <<= 1) {
        int add = (t >= o) ? s[t - o] : 0;
        __syncthreads();
        s[t] += add;
        __syncthreads();
    }
    if (t < nbk) {
        int ex = s[t] - v;   // exclusive
        bbase[t] = ex;
        fill[t]  = ex;
    }
    if (t == 0) { bbase[nbk] = E; row_ptr[n] = E; }
}

// ===========================================================================
// Stage 1: group edges by dst-bucket. Per-block LDS histogram -> per-edge
// rank; one global atomicAdd per (block,bucket) reserves a contiguous chunk;
// edges written as u32 {loc8<<24 | src24}. Every eb line is written by
// exactly one block -> no cross-XCD partial-line writebacks.
// ===========================================================================
__global__ __launch_bounds__(256) void k_binscatter(const int* __restrict__ ei,
                                                    int* __restrict__ fill,
                                                    uint_t* __restrict__ eb,
                                                    int E, int nbk)
{
    __shared__ int hist[NBK_MAX];
    __shared__ int gbase[NBK_MAX];
    const int t = threadIdx.x;
    const int e0 = blockIdx.x * EPB;

    for (int i = t; i < nbk; i += 256) hist[i] = 0;
    __syncthreads();

    int src[16], dst[16], rank[16];
    #pragma unroll
    for (int i = 0; i < 16; i++) {
        int e = e0 + i * 256 + t;
        bool ok = (e < E);
        src[i]  = ok ? ei[e] : 0;
        dst[i]  = ok ? ei[E + e] : -1;
        rank[i] = ok ? atomicAdd(&hist[dst[i] >> 8], 1) : 0;
    }
    __syncthreads();
    for (int b = t; b < nbk; b += 256) {
        int c = hist[b];
        gbase[b] = c ? atomicAdd(&fill[b], c) : 0;
    }
    __syncthreads();
    #pragma unroll
    for (int i = 0; i < 16; i++) {
        if (dst[i] >= 0) {
            int pos = gbase[dst[i] >> 8] + rank[i];
            eb[pos] = ((uint_t)(dst[i] & 255) << 24) | (uint_t)src[i];
        }
    }
}

// ===========================================================================
// Stage 2: one block per bucket. LDS histogram of the bucket's 256 node-locs
// -> block scan -> write row_ptr for these nodes (replaces k_scanfinal),
// then scatter src into the bucket's contiguous csr region (single-block-
// owned -> L2-local writes).
// ===========================================================================
__global__ __launch_bounds__(256) void k_csr_fine(const uint_t* __restrict__ eb,
                                                  const int* __restrict__ bbase,
                                                  int* __restrict__ row_ptr,
                                                  int* __restrict__ csr_src, int n)
{
    __shared__ int s[256];
    __shared__ int startS[256];
    __shared__ int hcnt[256];
    __shared__ int fl[256];
    const int b = blockIdx.x;
    const int t = threadIdx.x;
    const int base = bbase[b];
    const int cntb = bbase[b + 1] - base;

    hcnt[t] = 0; fl[t] = 0;
    __syncthreads();
    for (int i = t; i < cntb; i += 256)
        atomicAdd(&hcnt[eb[base + i] >> 24], 1);
    __syncthreads();

    int v = hcnt[t];
    s[t] = v;
    __syncthreads();
    for (int o = 1; o < 256; o <<= 1) {
        int add = (t >= o) ? s[t - o] : 0;
        __syncthreads();
        s[t] += add;
        __syncthreads();
    }
    startS[t] = s[t] - v;   // exclusive within bucket
    int node = b * 256 + t;
    if (node < n) row_ptr[node] = base + startS[t];
    __syncthreads();

    for (int i = t; i < cntb; i += 256) {
        uint_t e = eb[base + i];
        int loc = (int)(e >> 24);
        int src = (int)(e & 0x00ffffffu);
        int off = startS[loc] + atomicAdd(&fl[loc], 1);
        csr_src[base + off] = src;
    }
}

// ===========================================================================
// one-time casts: x -> bf16; weights -> transposed bf16 Wt[col][k]
// ===========================================================================
__global__ __launch_bounds__(256) void k_cast_x(const float* __restrict__ x,
                                                ushort_t* __restrict__ xb, int total8)
{
    int i = blockIdx.x * 256 + threadIdx.x;   // one thread = 8 elems
    if (i >= total8) return;
    const float4* p = (const float4*)(x + (size_t)i * 8);
    float4 a = p[0], b = p[1];
    uint4 st;
    st.x = (uint_t)f2b(a.x) | ((uint_t)f2b(a.y) << 16);
    st.y = (uint_t)f2b(a.z) | ((uint_t)f2b(a.w) << 16);
    st.z = (uint_t)f2b(b.x) | ((uint_t)f2b(b.y) << 16);
    st.w = (uint_t)f2b(b.z) | ((uint_t)f2b(b.w) << 16);
    *(uint4*)(xb + (size_t)i * 8) = st;
}

__global__ __launch_bounds__(256) void k_prep_w(const float* __restrict__ W1l,
                                                const float* __restrict__ W1r,
                                                const float* __restrict__ W2l,
                                                const float* __restrict__ W2r,
                                                ushort_t* __restrict__ Wt1,
                                                ushort_t* __restrict__ Wt2)
{
    int idx = blockIdx.x * 256 + threadIdx.x;   // 128 cols * 256 k
    if (idx >= 128 * 256) return;
    int c = idx >> 8, k = idx & 255;
    float v1 = (k < D) ? W1l[(size_t)k * D + c] : W1r[(size_t)(k - D) * D + c];
    float v2 = (k < D) ? W2l[(size_t)k * D + c] : W2r[(size_t)(k - D) * D + c];
    Wt1[idx] = f2b(v1);
    Wt2[idx] = f2b(v2);
}

// ===========================================================================
// Aggregation: one wave per dst node, bf16 gather (256 B rows, 16 lanes/row,
// 4 subwarps -> 4 edges in flight). All cross-lane ops wave-uniform;
// OOB steps neutralized branchlessly (id=0 row + zero mask).
// ===========================================================================
__global__ __launch_bounds__(256) void k_agg_csr(const ushort_t* __restrict__ featb,
                                                 const int* __restrict__ row_ptr,
                                                 const int* __restrict__ csr_src,
                                                 ushort_t* __restrict__ meanb, int n)
{
    int gtid = blockIdx.x * 256 + threadIdx.x;
    int v    = gtid >> 6;
    if (v >= n) return;
    int lane = threadIdx.x & 63;
    int sw   = lane >> 4;
    int sl   = lane & 15;

    int beg = row_ptr[v];
    int end = row_ptr[v + 1];

    const ushort_t* fb = featb + sl * 8;
    float acc[8] = {0.f, 0.f, 0.f, 0.f, 0.f, 0.f, 0.f, 0.f};

    for (int base = beg; base < end; base += 64) {
        int m = end - base; if (m > 64) m = 64;          // wave-uniform
        int id = (base + lane < end) ? csr_src[base + lane] : 0;
        int steps = (m + 3) >> 2;                        // wave-uniform
        #pragma unroll 4
        for (int t = 0; t < steps; t++) {
            int jj = sw + 4 * t;                         // <= 63 always
            int s  = __shfl(id, jj);                     // all 64 lanes active
            uint4 r = *(const uint4*)(fb + (size_t)s * D);
            uint_t msk = (jj < m) ? 0xffffffffu : 0u;
            r.x &= msk; r.y &= msk; r.z &= msk; r.w &= msk;
            acc_bf8(acc, r);
        }
    }

    #pragma unroll
    for (int q = 0; q < 8; q++) {
        acc[q] += __shfl_xor(acc[q], 16);
        acc[q] += __shfl_xor(acc[q], 32);
    }

    if (sw == 0) {
        float dinv = 1.0f / fmaxf((float)(end - beg), 1.0f);
        uint4 st;
        st.x = (uint_t)f2b(acc[0] * dinv) | ((uint_t)f2b(acc[1] * dinv) << 16);
        st.y = (uint_t)f2b(acc[2] * dinv) | ((uint_t)f2b(acc[3] * dinv) << 16);
        st.z = (uint_t)f2b(acc[4] * dinv) | ((uint_t)f2b(acc[5] * dinv) << 16);
        st.w = (uint_t)f2b(acc[6] * dinv) | ((uint_t)f2b(acc[7] * dinv) << 16);
        *(uint4*)(meanb + (size_t)v * D + sl * 8) = st;
    }
}

// ===========================================================================
// MFMA linear: out[r] = relu?( mean[r]@Wl + b + xin[r]@Wr ), K=256, LDS-free.
// ===========================================================================
__global__ __launch_bounds__(256) void k_linear_mfma(const ushort_t* __restrict__ meanb,
                                                     const ushort_t* __restrict__ xinb,
                                                     const ushort_t* __restrict__ Wt,
                                                     const float* __restrict__ bias,
                                                     float* __restrict__ outf,
                                                     ushort_t* __restrict__ outb,
                                                     int n, int relu)
{
    const int wave  = threadIdx.x >> 6;
    const int lane  = threadIdx.x & 63;
    const int kgrp  = lane >> 4;            // 0..3
    const int rbase = blockIdx.x * 128 + wave * 32;
    const int row0  = rbase + (lane & 15);
    const int row1  = row0 + 16;

    bf16x8 a0[8], a1[8];
    {
        const ushort_t* m0 = meanb + (size_t)row0 * D + kgrp * 8;
        const ushort_t* x0 = xinb  + (size_t)row0 * D + kgrp * 8;
        const ushort_t* m1 = meanb + (size_t)row1 * D + kgrp * 8;
        const ushort_t* x1 = xinb  + (size_t)row1 * D + kgrp * 8;
        #pragma unroll
        for (int kk = 0; kk < 4; kk++) {
            a0[kk]     = *(const bf16x8*)(m0 + kk * 32);
            a0[kk + 4] = *(const bf16x8*)(x0 + kk * 32);
            a1[kk]     = *(const bf16x8*)(m1 + kk * 32);
            a1[kk + 4] = *(const bf16x8*)(x1 + kk * 32);
        }
    }

    #pragma unroll
    for (int cb = 0; cb < 8; cb++) {
        const int col = cb * 16 + (lane & 15);
        const ushort_t* wrow = Wt + (size_t)col * 256 + kgrp * 8;
        f32x4 acc0 = {0.f, 0.f, 0.f, 0.f};
        f32x4 acc1 = {0.f, 0.f, 0.f, 0.f};
        #pragma unroll
        for (int kk = 0; kk < 8; kk++) {
            bf16x8 b = *(const bf16x8*)(wrow + kk * 32);
            acc0 = __builtin_amdgcn_mfma_f32_16x16x32_bf16(a0[kk], b, acc0, 0, 0, 0);
            acc1 = __builtin_amdgcn_mfma_f32_16x16x32_bf16(a1[kk], b, acc1, 0, 0, 0);
        }
        const float bv = bias[col];
        #pragma unroll
        for (int j = 0; j < 4; j++) {
            int r0w = rbase + kgrp * 4 + j;
            if (r0w < n) {
                float v = acc0[j] + bv;
                if (relu) v = fmaxf(v, 0.f);
                if (outf) outf[(size_t)r0w * D + col] = v;
                if (outb) outb[(size_t)r0w * D + col] = f2b(v);
            }
            int r1w = r0w + 16;
            if (r1w < n) {
                float v = acc1[j] + bv;
                if (relu) v = fmaxf(v, 0.f);
                if (outf) outf[(size_t)r1w * D + col] = v;
                if (outb) outb[(size_t)r1w * D + col] = f2b(v);
            }
        }
    }
}

extern "C" void kernel_launch(void* const* d_in, const int* in_sizes, int n_in,
                              void* d_out, int out_size, void* d_ws, size_t ws_size,
                              hipStream_t stream)
{
    const float* x   = (const float*)d_in[0];
    const int*   ei  = (const int*)d_in[1];
    const float* W1l = (const float*)d_in[2];
    const float* b1  = (const float*)d_in[3];
    const float* W1r = (const float*)d_in[4];
    const float* W2l = (const float*)d_in[5];
    const float* b2  = (const float*)d_in[6];
    const float* W2r = (const float*)d_in[7];
    float* out = (float*)d_out;

    const int n = in_sizes[0] / D;   // 100000
    const int E = in_sizes[1] / 2;   // 1600000
    const int nbk = (n + 255) / 256; // 391 buckets
    const int lin_blocks = (n + 127) / 128;          // 782
    const int npad = lin_blocks * 128;               // 100096

    // workspace layout (~90 MB; 102 MB proven OK in R1)
    size_t off = 0;
    auto alloc = [&](size_t bytes) { size_t o = off; off += (bytes + 511) & ~(size_t)511; return o; };
    char* ws = (char*)d_ws;
    int*      bcnt    = (int*)(ws + alloc((size_t)NBK_MAX * 4));
    int*      bbase   = (int*)(ws + alloc((size_t)(NBK_MAX + 1) * 4));
    int*      fill    = (int*)(ws + alloc((size_t)NBK_MAX * 4));
    int*      row_ptr = (int*)(ws + alloc((size_t)(n + 1) * 4));
    uint_t*   eb      = (uint_t*)(ws + alloc((size_t)E * 4));
    int*      csr_src = (int*)(ws + alloc((size_t)E * 4));
    ushort_t* meanb   = (ushort_t*)(ws + alloc((size_t)npad * D * 2));
    ushort_t* xb      = (ushort_t*)(ws + alloc((size_t)npad * D * 2));
    ushort_t* hb      = (ushort_t*)(ws + alloc((size_t)npad * D * 2));
    ushort_t* Wt1     = (ushort_t*)(ws + alloc((size_t)128 * 256 * 2));
    ushort_t* Wt2     = (ushort_t*)(ws + alloc((size_t)128 * 256 * 2));

    hipMemsetAsync(bcnt, 0, (size_t)NBK_MAX * 4, stream);

    dim3 gB((E + EPB - 1) / EPB), gN(nbk);
    // CSR build (reused by both layers)
    k_bucket_count<<<gB, 256, 0, stream>>>(ei, bcnt, E, nbk);
    k_scanb       <<<1, 512, 0, stream>>>(bcnt, nbk, bbase, fill, row_ptr, n, E);
    k_binscatter  <<<gB, 256, 0, stream>>>(ei, fill, eb, E, nbk);
    k_csr_fine    <<<gN, 256, 0, stream>>>(eb, bbase, row_ptr, csr_src, n);

    // one-time casts
    const int total8 = n * D / 8;
    k_cast_x<<<dim3((total8 + 255) / 256), 256, 0, stream>>>(x, xb, total8);
    k_prep_w<<<dim3(128), 256, 0, stream>>>(W1l, W1r, W2l, W2r, Wt1, Wt2);

    dim3 gAgg((n + 3) / 4);
    dim3 gLin(lin_blocks);

    // layer 1 (agg gathers bf16 x; linear emits bf16 h only)
    k_agg_csr    <<<gAgg, 256, 0, stream>>>(xb, row_ptr, csr_src, meanb, n);
    k_linear_mfma<<<gLin, 256, 0, stream>>>(meanb, xb, Wt1, b1, (float*)nullptr, hb, n, 1);

    // layer 2 (agg gathers bf16 h; linear writes fp32 out)
    k_agg_csr    <<<gAgg, 256, 0, stream>>>(hb, row_ptr, csr_src, meanb, n);
    k_linear_mfma<<<gLin, 256, 0, stream>>>(meanb, hb, Wt2, b2, out, (ushort_t*)nullptr, n, 0);
}